// Round 3
// baseline (167.604 us; speedup 1.0000x reference)
//
#include <hip/hip_runtime.h>

#define IO_DIM 64
#define WIDTH 16
#define HID 128
#define BS_ 1024                 // 64*16
#define TILE_ROWS 256
#define NTHREADS 256

// ws layout (floats): u[0..1024), w[1024..2048), bb[2048..2064), uw[2064..2080)

#define WAIT_LGKM0() asm volatile("s_waitcnt lgkmcnt(0)" ::: "memory")
#define WAIT_VM17()  asm volatile("s_waitcnt vmcnt(17)" ::: "memory")
#define BARRIER()    __builtin_amdgcn_s_barrier()

__device__ __forceinline__ float fast_tanh(float x) {
    float e = __expf(2.0f * x);
    return 1.0f - __fdividef(2.0f, e + 1.0f);
}

// async 16B/lane global->LDS; lds dest is wave-uniform base + lane*16
__device__ __forceinline__ void async_copy16(const float* gsrc, float4* lds_base) {
    __builtin_amdgcn_global_load_lds(
        (const __attribute__((address_space(1))) void*)gsrc,
        (__attribute__((address_space(3))) void*)lds_base,
        16, 0, 0);
}

__global__ __launch_bounds__(128) void cnf_prep(
    const float* __restrict__ t, const float* __restrict__ W1,
    const float* __restrict__ b1, const float* __restrict__ W2,
    const float* __restrict__ b2, const float* __restrict__ W3,
    const float* __restrict__ b3, float* __restrict__ ws)
{
    __shared__ float h1[HID];
    __shared__ float h2[HID];
    __shared__ float su[64], sw[64];
    const int tid = threadIdx.x;

    h1[tid] = tanhf(W1[tid] * t[0] + b1[tid]);
    __syncthreads();

    {
        float s = b2[tid];
        const float4* W2v = (const float4*)(W2 + tid * HID);
        #pragma unroll 8
        for (int k = 0; k < HID / 4; ++k) {
            float4 wv = W2v[k];
            s = fmaf(wv.x, h1[4 * k + 0], s);
            s = fmaf(wv.y, h1[4 * k + 1], s);
            s = fmaf(wv.z, h1[4 * k + 2], s);
            s = fmaf(wv.w, h1[4 * k + 3], s);
        }
        h2[tid] = tanhf(s);
    }
    __syncthreads();

    const int b = blockIdx.x;
    if (b < 16) {
        const int half = tid >> 6;   // 0 -> u, 1 -> w
        const int i = tid & 63;
        const int row = half * BS_ + b * 64 + i;
        float s = b3[row];
        const float4* W3v = (const float4*)(W3 + row * HID);
        #pragma unroll 8
        for (int k = 0; k < HID / 4; ++k) {
            float4 wv = W3v[k];
            s = fmaf(wv.x, h2[4 * k + 0], s);
            s = fmaf(wv.y, h2[4 * k + 1], s);
            s = fmaf(wv.z, h2[4 * k + 2], s);
            s = fmaf(wv.w, h2[4 * k + 3], s);
        }
        ws[half * BS_ + b * 64 + i] = s;
        if (half == 0) su[i] = s; else sw[i] = s;
        __syncthreads();
        if (tid < 64) {
            float p = su[tid] * sw[tid];
            #pragma unroll
            for (int m = 32; m >= 1; m >>= 1) p += __shfl_xor(p, m, 64);
            if (tid == 0) ws[2 * BS_ + WIDTH + b] = p;   // uw[b]
        }
    } else {
        if (tid < WIDTH) {
            const int row = 2 * BS_ + tid;
            float s = b3[row];
            const float4* W3v = (const float4*)(W3 + row * HID);
            #pragma unroll 8
            for (int k = 0; k < HID / 4; ++k) {
                float4 wv = W3v[k];
                s = fmaf(wv.x, h2[4 * k + 0], s);
                s = fmaf(wv.y, h2[4 * k + 1], s);
                s = fmaf(wv.z, h2[4 * k + 2], s);
                s = fmaf(wv.w, h2[4 * k + 3], s);
            }
            ws[2 * BS_ + tid] = s;   // bb[tid]
        }
    }
}

// stage one z tile into LDS buf (linear layout, granule-swizzled source).
// chunk c (1 KB) covers rows 4c..4c+3; lane l -> row 4c+(l>>4),
// global granule (l&15)^(row&15) lands at LDS slot (l&15) of that row.
__device__ __forceinline__ void stage_tile(const float* __restrict__ z,
                                           float4* buf, int base_row, int nrows,
                                           int wave, int lane)
{
    const int q = lane >> 4;
    const int gr = lane & 15;
    #pragma unroll
    for (int i = 0; i < 16; ++i) {
        const int c = wave * 16 + i;
        if (4 * c < nrows) {               // wave-uniform guard; nrows % 4 == 0
            const int r = 4 * c + q;
            const int g = gr ^ (r & 15);
            async_copy16(z + (size_t)(base_row + r) * 64 + (g << 2), buf + c * 64);
        }
    }
}

__global__ __launch_bounds__(NTHREADS) void cnf_main(
    const float* __restrict__ z, const float* __restrict__ ws,
    float* __restrict__ dz, float* __restrict__ dlog, int n)
{
    __shared__ __align__(16) float4 lbuf[2][TILE_ROWS * 16];   // 2 x 64 KB
    __shared__ __align__(16) float su[BS_];
    __shared__ __align__(16) float sw[BS_];
    __shared__ float sbb[WIDTH];
    __shared__ float suw[WIDTH];

    const int tid = threadIdx.x;
    const int lane = tid & 63;
    const int wave = tid >> 6;

    for (int idx = tid; idx < BS_; idx += NTHREADS) {
        su[idx] = ws[idx] * (1.0f / WIDTH);     // fold 1/16 into u
        sw[idx] = ws[BS_ + idx];
    }
    if (tid < WIDTH) {
        sbb[tid] = ws[2 * BS_ + tid];
        suw[tid] = ws[2 * BS_ + WIDTH + tid] * (-1.0f / WIDTH);
    }

    const int ntiles = (n + TILE_ROWS - 1) / TILE_ROWS;
    int tile = blockIdx.x;

    // prologue: prefetch first tile into buf 0
    if (tile < ntiles) {
        const int base = tile * TILE_ROWS;
        stage_tile(z, lbuf[0], base, min(TILE_ROWS, n - base), wave, lane);
    }
    __syncthreads();   // full drain once: weights + first tile resident

    const float4* su4 = (const float4*)su;
    const float4* sw4 = (const float4*)sw;

    int p = 0;
    for (; tile < ntiles; tile += gridDim.x, p ^= 1) {
        const int base = tile * TILE_ROWS;
        const int nrows = min(TILE_ROWS, n - base);
        const int ntile = tile + gridDim.x;

        // B: issue next-tile prefetch (fire-and-forget, stays in flight across barriers)
        if (ntile < ntiles) {
            const int nbase = ntile * TILE_ROWS;
            stage_tile(z, lbuf[p ^ 1], nbase, min(TILE_ROWS, n - nbase), wave, lane);
        }

        // C: compute this tile from lbuf[p]
        float4* buf = lbuf[p];
        if (tid < nrows) {
            const int sm = tid & 15;
            const float4* zrow = buf + tid * 16;

            float a[WIDTH];
            #pragma unroll
            for (int j = 0; j < WIDTH; ++j) a[j] = sbb[j];

            #pragma unroll
            for (int k4 = 0; k4 < 16; ++k4) {
                float4 z4 = zrow[k4 ^ sm];
                #pragma unroll
                for (int j = 0; j < WIDTH; ++j) {
                    float4 w4 = sw4[j * 16 + k4];
                    a[j] = fmaf(z4.x, w4.x, a[j]);
                    a[j] = fmaf(z4.y, w4.y, a[j]);
                    a[j] = fmaf(z4.z, w4.z, a[j]);
                    a[j] = fmaf(z4.w, w4.w, a[j]);
                }
            }

            float tr = 0.0f;
            #pragma unroll
            for (int j = 0; j < WIDTH; ++j) {
                float th = fast_tanh(a[j]);
                a[j] = th;
                tr = fmaf(1.0f - th * th, suw[j], tr);
            }
            dlog[base + tid] = tr;              // coalesced 4B/lane

            float4* mrow = buf + tid * 16;      // overwrite own row with dz
            #pragma unroll
            for (int k4 = 0; k4 < 16; ++k4) {
                float4 o = make_float4(0.f, 0.f, 0.f, 0.f);
                #pragma unroll
                for (int j = 0; j < WIDTH; ++j) {
                    float4 u4 = su4[j * 16 + k4];
                    o.x = fmaf(a[j], u4.x, o.x);
                    o.y = fmaf(a[j], u4.y, o.y);
                    o.z = fmaf(a[j], u4.z, o.z);
                    o.w = fmaf(a[j], u4.w, o.w);
                }
                mrow[k4 ^ sm] = o;
            }
        }

        // D: dz visible to all waves (LDS-only drain; prefetch loads stay in flight)
        WAIT_LGKM0();
        BARRIER();

        // E: cooperative contiguous store of dz
        {
            const int nvec = nrows * 16;
            float4* dzg = (float4*)dz + (size_t)base * 16;
            for (int idx = tid; idx < nvec; idx += NTHREADS) {
                const int r = idx >> 4, cg = idx & 15;
                dzg[idx] = buf[r * 16 + (cg ^ (r & 15))];
            }
        }

        // F: wait only for the prefetch loads (oldest 16). Younger vmem ops since
        // the prefetch: 1 dlog store + 16 dz stores = 17; in-order vmcnt
        // retirement => <=17 outstanding implies the 16 prefetch loads landed.
        WAIT_VM17();
        BARRIER();
    }
}

extern "C" void kernel_launch(void* const* d_in, const int* in_sizes, int n_in,
                              void* d_out, int out_size, void* d_ws, size_t ws_size,
                              hipStream_t stream) {
    const float* t  = (const float*)d_in[0];
    const float* z  = (const float*)d_in[1];
    const float* W1 = (const float*)d_in[2];
    const float* b1 = (const float*)d_in[3];
    const float* W2 = (const float*)d_in[4];
    const float* b2 = (const float*)d_in[5];
    const float* W3 = (const float*)d_in[6];
    const float* b3 = (const float*)d_in[7];

    const int n = in_sizes[1] / IO_DIM;   // 500000 (multiple of 4 assumed by stage_tile)
    float* ws   = (float*)d_ws;
    float* out  = (float*)d_out;
    float* dz   = out;
    float* dlog = out + (size_t)n * IO_DIM;

    cnf_prep<<<17, 128, 0, stream>>>(t, W1, b1, W2, b2, W3, b3, ws);

    const int ntiles = (n + TILE_ROWS - 1) / TILE_ROWS;
    const int grid = ntiles < 256 ? ntiles : 256;
    cnf_main<<<grid, NTHREADS, 0, stream>>>(z, ws, dz, dlog, n);
}

// Round 4
// 72.870 us; speedup vs baseline: 2.3000x; 2.3000x over previous
//
#include <hip/hip_runtime.h>

#define IO_DIM 64
#define WIDTH 16
#define HID 128
#define BS_ 1024                 // 64*16
#define TILE_ROWS 256
#define NTHREADS 256

// ws layout v2 (floats):
//   wT [64][16]  at    0..1024)   : wT[k][j] = w[j][k]
//   uT [64][16]  at 1024..2048)   : uT[d][j] = u[j][d] / 16
//   bb [16]      at 2048..2064)
//   nuw[16]      at 2064..2080)   : -uw[j] / 16

__device__ __forceinline__ float fast_tanh(float x) {
    float e = __expf(2.0f * x);
    return 1.0f - __fdividef(2.0f, e + 1.0f);
}

__global__ __launch_bounds__(128) void cnf_prep(
    const float* __restrict__ t, const float* __restrict__ W1,
    const float* __restrict__ b1, const float* __restrict__ W2,
    const float* __restrict__ b2, const float* __restrict__ W3,
    const float* __restrict__ b3, float* __restrict__ ws)
{
    __shared__ float h1[HID];
    __shared__ float h2[HID];
    __shared__ float su[64], sw[64];
    const int tid = threadIdx.x;

    h1[tid] = tanhf(W1[tid] * t[0] + b1[tid]);
    __syncthreads();

    {
        float s = b2[tid];
        const float4* W2v = (const float4*)(W2 + tid * HID);
        #pragma unroll 8
        for (int k = 0; k < HID / 4; ++k) {
            float4 wv = W2v[k];
            s = fmaf(wv.x, h1[4 * k + 0], s);
            s = fmaf(wv.y, h1[4 * k + 1], s);
            s = fmaf(wv.z, h1[4 * k + 2], s);
            s = fmaf(wv.w, h1[4 * k + 3], s);
        }
        h2[tid] = tanhf(s);
    }
    __syncthreads();

    const int b = blockIdx.x;
    if (b < 16) {
        // block b owns output row j=b of both u and w (64 elements each)
        const int half = tid >> 6;   // 0 -> u, 1 -> w
        const int i = tid & 63;      // element index (d or k)
        const int row = half * BS_ + b * 64 + i;
        float s = b3[row];
        const float4* W3v = (const float4*)(W3 + row * HID);
        #pragma unroll 8
        for (int k = 0; k < HID / 4; ++k) {
            float4 wv = W3v[k];
            s = fmaf(wv.x, h2[4 * k + 0], s);
            s = fmaf(wv.y, h2[4 * k + 1], s);
            s = fmaf(wv.z, h2[4 * k + 2], s);
            s = fmaf(wv.w, h2[4 * k + 3], s);
        }
        if (half == 0) {
            ws[1024 + i * 16 + b] = s * (1.0f / WIDTH);   // uT[d][j], scale folded
            su[i] = s;
        } else {
            ws[i * 16 + b] = s;                           // wT[k][j]
            sw[i] = s;
        }
        __syncthreads();
        if (tid < 64) {
            float p = su[tid] * sw[tid];
            #pragma unroll
            for (int m = 32; m >= 1; m >>= 1) p += __shfl_xor(p, m, 64);
            if (tid == 0) ws[2064 + b] = -p * (1.0f / WIDTH);   // nuw[b]
        }
    } else {
        if (tid < WIDTH) {
            const int row = 2 * BS_ + tid;
            float s = b3[row];
            const float4* W3v = (const float4*)(W3 + row * HID);
            #pragma unroll 8
            for (int k = 0; k < HID / 4; ++k) {
                float4 wv = W3v[k];
                s = fmaf(wv.x, h2[4 * k + 0], s);
                s = fmaf(wv.y, h2[4 * k + 1], s);
                s = fmaf(wv.z, h2[4 * k + 2], s);
                s = fmaf(wv.w, h2[4 * k + 3], s);
            }
            ws[2048 + tid] = s;   // bb
        }
    }
}

__global__ __launch_bounds__(NTHREADS, 4) void cnf_main(
    const float* __restrict__ z, const float* __restrict__ ws,
    float* __restrict__ dz, float* __restrict__ dlog, int n)
{
    // half-tile for dz assembly: [row][8 float4], XOR-swizzled slots. 32 KB.
    __shared__ __align__(16) float4 tile[TILE_ROWS * 8];

    const int tid = threadIdx.x;
    const int base = blockIdx.x * TILE_ROWS;
    const int row = base + tid;
    const bool valid = row < n;
    const int lrow = valid ? row : (n - 1);

    // burst-load own z row into registers (16B x 16, back-to-back: full line use)
    const float4* zg = (const float4*)z + (size_t)lrow * 16;
    float4 zr[16];
    #pragma unroll
    for (int i = 0; i < 16; ++i) zr[i] = zg[i];

    // phase 1: a[j] = bb[j] + sum_k z[k] * wT[k][j]   (weights via uniform s_load)
    float a[WIDTH];
    #pragma unroll
    for (int j = 0; j < WIDTH; ++j) a[j] = ws[2048 + j];

    #pragma unroll
    for (int kc = 0; kc < 16; ++kc) {
        const float4 zv = zr[kc];
        const float* wk = ws + kc * 64;   // wT rows 4kc..4kc+3, 64 contiguous floats
        #pragma unroll
        for (int j = 0; j < WIDTH; ++j) a[j] = fmaf(zv.x, wk[j],      a[j]);
        #pragma unroll
        for (int j = 0; j < WIDTH; ++j) a[j] = fmaf(zv.y, wk[16 + j], a[j]);
        #pragma unroll
        for (int j = 0; j < WIDTH; ++j) a[j] = fmaf(zv.z, wk[32 + j], a[j]);
        #pragma unroll
        for (int j = 0; j < WIDTH; ++j) a[j] = fmaf(zv.w, wk[48 + j], a[j]);
    }

    // tanh + trace
    float tr = 0.0f;
    #pragma unroll
    for (int j = 0; j < WIDTH; ++j) {
        float th = fast_tanh(a[j]);
        a[j] = th;
        tr = fmaf(1.0f - th * th, ws[2064 + j], tr);
    }
    if (valid) dlog[row] = tr;

    // phase 2 in two halves (32 cols each) through the 32 KB LDS tile
    const float* uT = ws + 1024;
    const int nrows = min(TILE_ROWS, n - base);
    const int nvec = nrows * 8;
    float4* dzv = (float4*)dz;

    #pragma unroll
    for (int half = 0; half < 2; ++half) {
        #pragma unroll
        for (int dc = 0; dc < 8; ++dc) {
            const int d0 = half * 32 + dc * 4;
            float4 o = make_float4(0.f, 0.f, 0.f, 0.f);
            #pragma unroll
            for (int j = 0; j < WIDTH; ++j) {
                const float th = a[j];
                o.x = fmaf(th, uT[(d0 + 0) * 16 + j], o.x);
                o.y = fmaf(th, uT[(d0 + 1) * 16 + j], o.y);
                o.z = fmaf(th, uT[(d0 + 2) * 16 + j], o.z);
                o.w = fmaf(th, uT[(d0 + 3) * 16 + j], o.w);
            }
            tile[tid * 8 + (dc ^ (tid & 7))] = o;   // swizzled: banks spread
        }
        __syncthreads();
        // cooperative store: each row's 32 floats (128 B) contiguous in dz
        for (int idx = tid; idx < nvec; idx += NTHREADS) {
            const int r = idx >> 3, c = idx & 7;
            dzv[((size_t)(base + r)) * 16 + half * 8 + c] =
                tile[r * 8 + (c ^ (r & 7))];
        }
        __syncthreads();   // tile safe to overwrite in next half
    }
}

extern "C" void kernel_launch(void* const* d_in, const int* in_sizes, int n_in,
                              void* d_out, int out_size, void* d_ws, size_t ws_size,
                              hipStream_t stream) {
    const float* t  = (const float*)d_in[0];
    const float* z  = (const float*)d_in[1];
    const float* W1 = (const float*)d_in[2];
    const float* b1 = (const float*)d_in[3];
    const float* W2 = (const float*)d_in[4];
    const float* b2 = (const float*)d_in[5];
    const float* W3 = (const float*)d_in[6];
    const float* b3 = (const float*)d_in[7];

    const int n = in_sizes[1] / IO_DIM;   // 500000
    float* ws   = (float*)d_ws;
    float* out  = (float*)d_out;
    float* dz   = out;
    float* dlog = out + (size_t)n * IO_DIM;

    cnf_prep<<<17, 128, 0, stream>>>(t, W1, b1, W2, b2, W3, b3, ws);

    const int grid = (n + TILE_ROWS - 1) / TILE_ROWS;
    cnf_main<<<grid, NTHREADS, 0, stream>>>(z, ws, dz, dlog, n);
}